// Round 4
// baseline (30.292 us; speedup 1.0000x reference)
//
#include <hip/hip_runtime.h>
#include <hip/hip_bf16.h>
#include <math.h>

// NCM classifier: B=1024, C=500, F=512 (fp32 in/out).
//   xs = x / variance[0]
//   dist[b][c] = sqrt(sum_f (xs[b][f] - means[c][f])^2)
//   out = concat(softmax(-dist, axis=1), -dist, dist)   // each [B][C]
//
// dist^2 = ||xs_b||^2 + ||m_c||^2 - 2*(xs . m): bf16 MFMA for the cross term.
// Fully fused: each 1-wave block loads fp32 tiles straight from global
// (inputs 3MB -> L2-resident), converts to bf16 in-register, accumulates
// row norms in-register (shfl_xor over the 4 k-group lanes), MFMAs, and
// writes -dist / dist. No prep kernel, no workspace.
#define NB 1024
#define NC 500
#define NF 512

typedef __attribute__((ext_vector_type(8))) short bf16x8;
typedef __attribute__((ext_vector_type(4))) float f32x4;

union bfpack { bf16x8 v; __hip_bfloat162 h[4]; };

// scale+convert 8 floats -> bf16x8, accumulate sum of squares of scaled vals
static __device__ inline bf16x8 cvt8(float4 u0, float4 u1, float scale, float& nacc) {
    u0.x *= scale; u0.y *= scale; u0.z *= scale; u0.w *= scale;
    u1.x *= scale; u1.y *= scale; u1.z *= scale; u1.w *= scale;
    bfpack p;
    p.h[0] = __float22bfloat162_rn(make_float2(u0.x, u0.y));
    p.h[1] = __float22bfloat162_rn(make_float2(u0.z, u0.w));
    p.h[2] = __float22bfloat162_rn(make_float2(u1.x, u1.y));
    p.h[3] = __float22bfloat162_rn(make_float2(u1.z, u1.w));
    nacc = fmaf(u0.x, u0.x, nacc); nacc = fmaf(u0.y, u0.y, nacc);
    nacc = fmaf(u0.z, u0.z, nacc); nacc = fmaf(u0.w, u0.w, nacc);
    nacc = fmaf(u1.x, u1.x, nacc); nacc = fmaf(u1.y, u1.y, nacc);
    nacc = fmaf(u1.z, u1.z, nacc); nacc = fmaf(u1.w, u1.w, nacc);
    return p.v;
}

// One wave per block, 32x32 output tile (2x2 fragments of 16x16x32 bf16).
// grid = (1024/32, 512/32) = (32, 16) = 512 blocks -> 2 waves/CU.
__global__ __launch_bounds__(64) void ncm_dist_kernel(
    const float* __restrict__ x, const float* __restrict__ means,
    const float* __restrict__ variance, float* __restrict__ out)
{
    const int lane = threadIdx.x;
    const int g  = lane >> 4;   // k-group 0..3 (8 K-elems each)
    const int fr = lane & 15;   // fragment row/col
    const int b0 = blockIdx.x * 32;
    const int c0 = blockIdx.y * 32;
    const float inv_var = 1.0f / variance[0];

    const float* pa0 = x + (size_t)(b0 + fr) * NF + g * 8;
    const float* pa1 = pa0 + (size_t)16 * NF;
    const int cB0 = c0 + fr, cB1 = cB0 + 16;
    const bool vB0 = cB0 < NC, vB1 = cB1 < NC;
    const float* pb0 = means + (size_t)cB0 * NF + g * 8;
    const float* pb1 = means + (size_t)cB1 * NF + g * 8;

    f32x4 acc00 = {0.f, 0.f, 0.f, 0.f};
    f32x4 acc01 = acc00, acc10 = acc00, acc11 = acc00;
    float na0 = 0.f, na1 = 0.f, nb0 = 0.f, nb1 = 0.f;
    const float4 z4 = make_float4(0.f, 0.f, 0.f, 0.f);

    #pragma unroll 4
    for (int k = 0; k < NF; k += 32) {
        float4 a0lo = *reinterpret_cast<const float4*>(pa0 + k);
        float4 a0hi = *reinterpret_cast<const float4*>(pa0 + k + 4);
        float4 a1lo = *reinterpret_cast<const float4*>(pa1 + k);
        float4 a1hi = *reinterpret_cast<const float4*>(pa1 + k + 4);
        float4 b0lo = vB0 ? *reinterpret_cast<const float4*>(pb0 + k)     : z4;
        float4 b0hi = vB0 ? *reinterpret_cast<const float4*>(pb0 + k + 4) : z4;
        float4 b1lo = vB1 ? *reinterpret_cast<const float4*>(pb1 + k)     : z4;
        float4 b1hi = vB1 ? *reinterpret_cast<const float4*>(pb1 + k + 4) : z4;

        bf16x8 fa0 = cvt8(a0lo, a0hi, inv_var, na0);
        bf16x8 fa1 = cvt8(a1lo, a1hi, inv_var, na1);
        bf16x8 fb0 = cvt8(b0lo, b0hi, 1.0f, nb0);
        bf16x8 fb1 = cvt8(b1lo, b1hi, 1.0f, nb1);

        acc00 = __builtin_amdgcn_mfma_f32_16x16x32_bf16(fa0, fb0, acc00, 0, 0, 0);
        acc01 = __builtin_amdgcn_mfma_f32_16x16x32_bf16(fa0, fb1, acc01, 0, 0, 0);
        acc10 = __builtin_amdgcn_mfma_f32_16x16x32_bf16(fa1, fb0, acc10, 0, 0, 0);
        acc11 = __builtin_amdgcn_mfma_f32_16x16x32_bf16(fa1, fb1, acc11, 0, 0, 0);
    }

    // full-row norms: sum the 4 k-group partials (lanes fr, fr+16, fr+32, fr+48)
    na0 += __shfl_xor(na0, 16, 64); na0 += __shfl_xor(na0, 32, 64);
    na1 += __shfl_xor(na1, 16, 64); na1 += __shfl_xor(na1, 32, 64);
    nb0 += __shfl_xor(nb0, 16, 64); nb0 += __shfl_xor(nb0, 32, 64);
    nb1 += __shfl_xor(nb1, 16, 64); nb1 += __shfl_xor(nb1, 32, 64);

    // C/D layout (m89/m91): col = lane&15, row = (lane>>4)*4 + reg
    const int rg = g * 4;
    float nxr0[4], nxr1[4];
    #pragma unroll
    for (int r = 0; r < 4; ++r) {
        nxr0[r] = __shfl(na0, rg + r, 64);  // ||xs_{b0+rg+r}||^2
        nxr1[r] = __shfl(na1, rg + r, 64);  // ||xs_{b0+16+rg+r}||^2
    }

    float* expo  = out + (size_t)NB * NC;
    float* cdiff = out + (size_t)2 * NB * NC;

    #pragma unroll
    for (int wm = 0; wm < 2; ++wm) {
        f32x4 g_lo = wm ? acc10 : acc00;
        f32x4 g_hi = wm ? acc11 : acc01;
        #pragma unroll
        for (int r = 0; r < 4; ++r) {
            int b = b0 + wm * 16 + rg + r;
            float nxb = wm ? nxr1[r] : nxr0[r];
            if (vB0) {
                float d2 = nxb + nb0 - 2.0f * g_lo[r];
                float d = sqrtf(fmaxf(d2, 0.0f));
                expo[(size_t)b * NC + cB0]  = -d;
                cdiff[(size_t)b * NC + cB0] = d;
            }
            if (vB1) {
                float d2 = nxb + nb1 - 2.0f * g_hi[r];
                float d = sqrtf(fmaxf(d2, 0.0f));
                expo[(size_t)b * NC + cB1]  = -d;
                cdiff[(size_t)b * NC + cB1] = d;
            }
        }
    }
}

// Softmax over C=500: one wave per row, no LDS, no __syncthreads.
// Row byte offset b*2000 is 16B-aligned (2000 = 125*16) -> float4 legal.
__global__ __launch_bounds__(64) void ncm_softmax_kernel(float* __restrict__ out)
{
    const int b = blockIdx.x;
    const int lane = threadIdx.x;
    const float* expo = out + (size_t)NB * NC + (size_t)b * NC;
    float* probs = out + (size_t)b * NC;

    const int base = lane * 8;
    const bool val0 = base + 3 < NC;   // lanes 0..62
    const bool val1 = base + 7 < NC;   // lanes 0..61
    const float4 ninf = make_float4(-1e30f, -1e30f, -1e30f, -1e30f);

    float4 v0 = val0 ? *reinterpret_cast<const float4*>(&expo[base])     : ninf;
    float4 v1 = val1 ? *reinterpret_cast<const float4*>(&expo[base + 4]) : ninf;

    float m = fmaxf(fmaxf(fmaxf(v0.x, v0.y), fmaxf(v0.z, v0.w)),
                    fmaxf(fmaxf(v1.x, v1.y), fmaxf(v1.z, v1.w)));
    #pragma unroll
    for (int off = 32; off > 0; off >>= 1)
        m = fmaxf(m, __shfl_xor(m, off, 64));

    float4 e0, e1;
    e0.x = expf(v0.x - m); e0.y = expf(v0.y - m);
    e0.z = expf(v0.z - m); e0.w = expf(v0.w - m);
    e1.x = expf(v1.x - m); e1.y = expf(v1.y - m);
    e1.z = expf(v1.z - m); e1.w = expf(v1.w - m);

    float s = e0.x + e0.y + e0.z + e0.w + e1.x + e1.y + e1.z + e1.w;
    #pragma unroll
    for (int off = 32; off > 0; off >>= 1)
        s += __shfl_xor(s, off, 64);
    float inv = 1.0f / s;

    e0.x *= inv; e0.y *= inv; e0.z *= inv; e0.w *= inv;
    e1.x *= inv; e1.y *= inv; e1.z *= inv; e1.w *= inv;

    if (val0) *reinterpret_cast<float4*>(&probs[base])     = e0;
    if (val1) *reinterpret_cast<float4*>(&probs[base + 4]) = e1;
}

extern "C" void kernel_launch(void* const* d_in, const int* in_sizes, int n_in,
                              void* d_out, int out_size, void* d_ws, size_t ws_size,
                              hipStream_t stream) {
    const float* x        = (const float*)d_in[0];
    const float* means    = (const float*)d_in[1];
    const float* variance = (const float*)d_in[2];
    float* out = (float*)d_out;

    dim3 g(NB / 32, (NC + 31) / 32);  // (32, 16) = 512 single-wave blocks
    ncm_dist_kernel<<<g, 64, 0, stream>>>(x, means, variance, out);
    ncm_softmax_kernel<<<NB, 64, 0, stream>>>(out);
}